// Round 2
// baseline (1414.981 us; speedup 1.0000x reference)
//
#include <hip/hip_runtime.h>
#include <hip/hip_bf16.h>

#define NB 100
#define NT 500
#define CIN 300
#define COUT 500
#define M_TOT (NB * NT)   // 50000

constexpr int BM = 128, BN = 128, BK = 16;
constexpr int LDA = BM + 4;   // 132 floats; k*132 keeps float4 alignment (132%4==0)

// C[m][o] = sum_k X[m][k] * W[o][k]
__global__ __launch_bounds__(256, 4) void gemm_f32(
    const float* __restrict__ X, const float* __restrict__ W, float* __restrict__ C)
{
    __shared__ float As[BK][LDA];
    __shared__ float Bs[BK][LDA];

    const int mtile = blockIdx.x >> 2;      // ntile fastest -> 4 consecutive blocks share X tile
    const int ntile = blockIdx.x & 3;
    const int m0 = mtile * BM, n0 = ntile * BN;

    const int tid  = threadIdx.x;
    const int lane = tid & 63;
    const int wid  = tid >> 6;              // 4 waves, 2x2 grid of 64x64 wave tiles
    const int wmb  = (wid >> 1) << 6;       // 0 or 64
    const int wnb  = (wid & 1) << 6;        // 0 or 64
    const int r4   = (lane >> 3) << 2;      // 0,4,...,28
    const int c4   = (lane & 7) << 2;       // 0,4,...,28

    // staging: 4 lanes per row, each lane one float4 along k; two 64-row halves
    const int srow = tid >> 2;              // 0..63
    const int skq  = (tid & 3) << 2;        // 0,4,8,12

    const int mr0 = min(m0 + srow,      M_TOT - 1);
    const int mr1 = min(m0 + 64 + srow, M_TOT - 1);
    const int or0 = min(n0 + srow,      COUT - 1);
    const int or1 = min(n0 + 64 + srow, COUT - 1);
    const float* xp0 = X + (size_t)mr0 * CIN;
    const float* xp1 = X + (size_t)mr1 * CIN;
    const float* wp0 = W + (size_t)or0 * CIN;
    const float* wp1 = W + (size_t)or1 * CIN;

    float acc[8][8];
    #pragma unroll
    for (int i = 0; i < 8; ++i)
        #pragma unroll
        for (int j = 0; j < 8; ++j) acc[i][j] = 0.f;

    auto ld4 = [](const float* p, int ks) -> float4 {
        // CIN=300 is float4-granular; ks ranges over multiples of 4 up to 300.
        return (ks < CIN) ? *(const float4*)(p + ks) : make_float4(0.f, 0.f, 0.f, 0.f);
    };

    float4 xa0 = ld4(xp0, skq);
    float4 xa1 = ld4(xp1, skq);
    float4 wb0 = ld4(wp0, skq);
    float4 wb1 = ld4(wp1, skq);

    constexpr int NSTEP = (CIN + BK - 1) / BK;   // 19 (k padded 300->304 with zeros)
    for (int step = 0; step < NSTEP; ++step) {
        __syncthreads();   // previous iter's reads done: safe to overwrite LDS
        As[skq + 0][srow]      = xa0.x; As[skq + 1][srow]      = xa0.y;
        As[skq + 2][srow]      = xa0.z; As[skq + 3][srow]      = xa0.w;
        As[skq + 0][64 + srow] = xa1.x; As[skq + 1][64 + srow] = xa1.y;
        As[skq + 2][64 + srow] = xa1.z; As[skq + 3][64 + srow] = xa1.w;
        Bs[skq + 0][srow]      = wb0.x; Bs[skq + 1][srow]      = wb0.y;
        Bs[skq + 2][srow]      = wb0.z; Bs[skq + 3][srow]      = wb0.w;
        Bs[skq + 0][64 + srow] = wb1.x; Bs[skq + 1][64 + srow] = wb1.y;
        Bs[skq + 2][64 + srow] = wb1.z; Bs[skq + 3][64 + srow] = wb1.w;
        __syncthreads();

        if (step + 1 < NSTEP) {           // issue next tile's loads; latency hides under FMAs
            const int kn = (step + 1) * BK + skq;
            xa0 = ld4(xp0, kn);
            xa1 = ld4(xp1, kn);
            wb0 = ld4(wp0, kn);
            wb1 = ld4(wp1, kn);
        }

        #pragma unroll
        for (int k = 0; k < BK; ++k) {
            // each read: 8 unique addrs x 16B = all 32 banks once, 8-lane broadcast
            float4 a0 = *(const float4*)&As[k][wmb + r4];
            float4 a1 = *(const float4*)&As[k][wmb + 32 + r4];
            float4 b0 = *(const float4*)&Bs[k][wnb + c4];
            float4 b1 = *(const float4*)&Bs[k][wnb + 32 + c4];
            float a[8] = {a0.x, a0.y, a0.z, a0.w, a1.x, a1.y, a1.z, a1.w};
            float b[8] = {b0.x, b0.y, b0.z, b0.w, b1.x, b1.y, b1.z, b1.w};
            #pragma unroll
            for (int i = 0; i < 8; ++i)
                #pragma unroll
                for (int j = 0; j < 8; ++j)
                    acc[i][j] += a[i] * b[j];
        }
    }

    // epilogue: rows m0+wmb+{4r..4r+3, 32+4r..}, cols n0+wnb+{4c..4c+3, 32+4c..}
    #pragma unroll
    for (int h = 0; h < 2; ++h) {
        #pragma unroll
        for (int i = 0; i < 4; ++i) {
            const int m = m0 + wmb + h * 32 + r4 + i;
            if (m >= M_TOT) continue;
            float* cp = C + (size_t)m * COUT;
            const int col0 = n0 + wnb + c4;
            const int col1 = col0 + 32;
            const int ai = h * 4 + i;
            if (col0 + 3 < COUT)
                *(float4*)(cp + col0) = make_float4(acc[ai][0], acc[ai][1], acc[ai][2], acc[ai][3]);
            if (col1 + 3 < COUT)
                *(float4*)(cp + col1) = make_float4(acc[ai][4], acc[ai][5], acc[ai][6], acc[ai][7]);
        }
    }
}

// In-place LIF scan over t for each neuron n = b*COUT + o. threshold == 1.
__global__ __launch_bounds__(256) void lif_scan(
    const float* __restrict__ alpha, float* __restrict__ C)
{
    const int n = blockIdx.x * blockDim.x + threadIdx.x;
    if (n >= NB * COUT) return;
    const int b = n / COUT, o = n % COUT;
    const float a = alpha[n];
    float v = 0.f;
    float* p = C + (size_t)b * NT * COUT + o;

    constexpr int U = 10;   // 500 = 50 * 10
    for (int t0 = 0; t0 < NT; t0 += U) {
        float xl[U];
        #pragma unroll
        for (int u = 0; u < U; ++u) xl[u] = p[(size_t)(t0 + u) * COUT];
        float s[U];
        #pragma unroll
        for (int u = 0; u < U; ++u) {
            float vp = a * v + xl[u];
            vp = fmaxf(vp, -1.f);
            float sp = (vp >= 1.f) ? floorf(vp) : 0.f;
            v = vp - sp;
            s[u] = sp;
        }
        #pragma unroll
        for (int u = 0; u < U; ++u) p[(size_t)(t0 + u) * COUT] = s[u];
    }
}

extern "C" void kernel_launch(void* const* d_in, const int* in_sizes, int n_in,
                              void* d_out, int out_size, void* d_ws, size_t ws_size,
                              hipStream_t stream) {
    const float* X     = (const float*)d_in[0];   // [100,500,300]
    const float* W     = (const float*)d_in[1];   // [500,300]
    const float* alpha = (const float*)d_in[2];   // [50000]
    float* C = (float*)d_out;                     // [100,500,500]

    const int mtiles = (M_TOT + BM - 1) / BM;     // 391
    const int ntiles = (COUT + BN - 1) / BN;      // 4
    gemm_f32<<<dim3(mtiles * ntiles), dim3(256), 0, stream>>>(X, W, C);

    const int nneur = NB * COUT;                  // 50000
    lif_scan<<<dim3((nneur + 255) / 256), dim3(256), 0, stream>>>(alpha, C);
}

// Round 3
// 271.973 us; speedup vs baseline: 5.2027x; 5.2027x over previous
//
#include <hip/hip_runtime.h>
#include <hip/hip_bf16.h>

#define NB 100
#define NT 500
#define CIN 300
#define COUT 500
#define M_TOT (NB * NT)   // 50000

constexpr int BM = 128, BN = 128, BK = 32;
constexpr int LDA = BM + 4;   // 132: k*132 keeps float4 alignment, breaks pow2 stride

// C[m][o] = sum_k X[m][k] * W[o][k]   (X: [M,300], W: [500,300], C: [M,500])
__global__ __launch_bounds__(256) void gemm_f32(
    const float* __restrict__ X, const float* __restrict__ W, float* __restrict__ C)
{
    __shared__ float As[BK][LDA];
    __shared__ float Bs[BK][LDA];

    const int ntiles_n = (COUT + BN - 1) / BN;  // 4
    const int mtile = blockIdx.x / ntiles_n;    // ntile fastest: 4 consecutive blocks share X tile
    const int ntile = blockIdx.x % ntiles_n;
    const int m0 = mtile * BM, n0 = ntile * BN;

    const int tid  = threadIdx.x;
    const int lane = tid & 63;
    const int wid  = tid >> 6;              // 4 waves: 2x2 grid of 64x64 wave tiles
    const int wmb  = (wid >> 1) << 6;       // 0 or 64
    const int wnb  = (wid & 1) << 6;        // 0 or 64
    const int r4   = (lane >> 3) << 2;      // 0,4,...,28
    const int c4   = (lane & 7) << 2;       // 0,4,...,28

    // staging: 8 lanes per row, each lane one float4 along k
    const int lr = tid >> 3;                // 0..31 : row within 32-row group
    const int lk = (tid & 7) << 2;          // 0,4,...,28 : k offset (float4)

    float acc[8][8];
    #pragma unroll
    for (int i = 0; i < 8; ++i)
        #pragma unroll
        for (int j = 0; j < 8; ++j) acc[i][j] = 0.f;

    for (int k0 = 0; k0 < CIN; k0 += BK) {
        const int kk = k0 + lk;
        const bool kv = (kk < CIN);   // CIN divisible by 4, so float4-granular
        #pragma unroll
        for (int p = 0; p < 4; ++p) {
            int row = p * 32 + lr;
            int m = m0 + row;
            float4 v = make_float4(0.f, 0.f, 0.f, 0.f);
            if (kv && m < M_TOT) v = *(const float4*)(X + (size_t)m * CIN + kk);
            As[lk + 0][row] = v.x; As[lk + 1][row] = v.y;
            As[lk + 2][row] = v.z; As[lk + 3][row] = v.w;
        }
        #pragma unroll
        for (int p = 0; p < 4; ++p) {
            int row = p * 32 + lr;
            int o = n0 + row;
            float4 v = make_float4(0.f, 0.f, 0.f, 0.f);
            if (kv && o < COUT) v = *(const float4*)(W + (size_t)o * CIN + kk);
            Bs[lk + 0][row] = v.x; Bs[lk + 1][row] = v.y;
            Bs[lk + 2][row] = v.z; Bs[lk + 3][row] = v.w;
        }
        __syncthreads();
        #pragma unroll 8
        for (int k = 0; k < BK; ++k) {
            // each read: 8 unique contiguous addrs x 16B = all 32 banks once, 8-lane broadcast
            float4 a0 = *(const float4*)&As[k][wmb + r4];
            float4 a1 = *(const float4*)&As[k][wmb + 32 + r4];
            float4 b0 = *(const float4*)&Bs[k][wnb + c4];
            float4 b1 = *(const float4*)&Bs[k][wnb + 32 + c4];
            float a[8] = {a0.x, a0.y, a0.z, a0.w, a1.x, a1.y, a1.z, a1.w};
            float b[8] = {b0.x, b0.y, b0.z, b0.w, b1.x, b1.y, b1.z, b1.w};
            #pragma unroll
            for (int i = 0; i < 8; ++i)
                #pragma unroll
                for (int j = 0; j < 8; ++j)
                    acc[i][j] += a[i] * b[j];
        }
        __syncthreads();
    }

    // epilogue: rows m0+wmb+{h*32+r4+i}, cols n0+wnb+{c4.., 32+c4..}
    #pragma unroll
    for (int h = 0; h < 2; ++h) {
        #pragma unroll
        for (int i = 0; i < 4; ++i) {
            const int m = m0 + wmb + h * 32 + r4 + i;
            if (m >= M_TOT) continue;
            float* cp = C + (size_t)m * COUT;
            const int col0 = n0 + wnb + c4;        // COUT%4==0: float4s never straddle the edge
            const int col1 = col0 + 32;
            const int ai = h * 4 + i;
            if (col0 < COUT)
                *(float4*)(cp + col0) = make_float4(acc[ai][0], acc[ai][1], acc[ai][2], acc[ai][3]);
            if (col1 < COUT)
                *(float4*)(cp + col1) = make_float4(acc[ai][4], acc[ai][5], acc[ai][6], acc[ai][7]);
        }
    }
}

// In-place LIF scan over t for each neuron n = b*COUT + o. threshold == 1.
__global__ __launch_bounds__(256) void lif_scan(
    const float* __restrict__ alpha, float* __restrict__ C)
{
    const int n = blockIdx.x * blockDim.x + threadIdx.x;
    if (n >= NB * COUT) return;
    const int b = n / COUT, o = n % COUT;
    const float a = alpha[n];
    float v = 0.f;
    float* p = C + (size_t)b * NT * COUT + o;

    constexpr int U = 10;   // 500 = 50 * 10
    for (int t0 = 0; t0 < NT; t0 += U) {
        float xl[U];
        #pragma unroll
        for (int u = 0; u < U; ++u) xl[u] = p[(size_t)(t0 + u) * COUT];
        float s[U];
        #pragma unroll
        for (int u = 0; u < U; ++u) {
            float vp = a * v + xl[u];
            vp = fmaxf(vp, -1.f);
            float sp = (vp >= 1.f) ? floorf(vp) : 0.f;
            v = vp - sp;
            s[u] = sp;
        }
        #pragma unroll
        for (int u = 0; u < U; ++u) p[(size_t)(t0 + u) * COUT] = s[u];
    }
}

extern "C" void kernel_launch(void* const* d_in, const int* in_sizes, int n_in,
                              void* d_out, int out_size, void* d_ws, size_t ws_size,
                              hipStream_t stream) {
    const float* X     = (const float*)d_in[0];   // [100,500,300]
    const float* W     = (const float*)d_in[1];   // [500,300]
    const float* alpha = (const float*)d_in[2];   // [50000]
    float* C = (float*)d_out;                     // [100,500,500]

    const int mtiles = (M_TOT + BM - 1) / BM;     // 391
    const int ntiles = (COUT + BN - 1) / BN;      // 4
    gemm_f32<<<dim3(mtiles * ntiles), dim3(256), 0, stream>>>(X, W, C);

    const int nneur = NB * COUT;                  // 50000
    lif_scan<<<dim3((nneur + 255) / 256), dim3(256), 0, stream>>>(alpha, C);
}